// Round 4
// baseline (731.198 us; speedup 1.0000x reference)
//
#include <hip/hip_runtime.h>

// Problem constants (fixed by reference): B=4, S=2048 -> N_TOK=8192; IN=OUT=4096; POOLS=128; top_k=2.
#define K_DIM  4096
#define N_OUT  4096
#define N_TOK  8192
#define N_POOL 128

typedef __bf16 bf16x8 __attribute__((ext_vector_type(8)));
typedef float  f32x4  __attribute__((ext_vector_type(4)));
typedef unsigned short u16x8 __attribute__((ext_vector_type(8)));

#define AS1 __attribute__((address_space(1)))
#define AS3 __attribute__((address_space(3)))

__device__ __forceinline__ unsigned short f2bf(float f) {
    union { float f; unsigned u; } v; v.f = f;
    unsigned r = v.u + 0x7fffu + ((v.u >> 16) & 1u);   // RNE
    return (unsigned short)(r >> 16);
}
__device__ __forceinline__ float bf2f(unsigned short b) {
    union { unsigned u; float f; } v; v.u = ((unsigned)b) << 16;
    return v.f;
}

// ---------------- kernel 1: w0 fp32 -> bf16 ----------------
__global__ __launch_bounds__(256) void k_convert_w0(const float* __restrict__ w0,
                                                    unsigned short* __restrict__ w0b) {
    size_t base = ((size_t)blockIdx.x * 256 + threadIdx.x) * 8;
    float4 a = *(const float4*)(w0 + base);
    float4 b = *(const float4*)(w0 + base + 4);
    u16x8 r;
    r[0] = f2bf(a.x); r[1] = f2bf(a.y); r[2] = f2bf(a.z); r[3] = f2bf(a.w);
    r[4] = f2bf(b.x); r[5] = f2bf(b.y); r[6] = f2bf(b.z); r[7] = f2bf(b.w);
    *(u16x8*)(w0b + base) = r;
}

// ---------------- kernel 1a: x fp32 -> bf16 plane (identical bits to old in-router f2bf) ----
__global__ __launch_bounds__(256) void k_convert_x(const float* __restrict__ x,
                                                   unsigned short* __restrict__ xh) {
    size_t base = ((size_t)blockIdx.x * 256 + threadIdx.x) * 8;
    float4 a = *(const float4*)(x + base);
    float4 b = *(const float4*)(x + base + 4);
    u16x8 r;
    r[0] = f2bf(a.x); r[1] = f2bf(a.y); r[2] = f2bf(a.z); r[3] = f2bf(a.w);
    r[4] = f2bf(b.x); r[5] = f2bf(b.y); r[6] = f2bf(b.z); r[7] = f2bf(b.w);
    *(u16x8*)(xh + base) = r;
}

// ---------------- kernel 1c: wr fp32 -> bf16 ----------------
__global__ __launch_bounds__(256) void k_convert_wr(const float* __restrict__ wr,
                                                    unsigned short* __restrict__ wrh) {
    size_t base = ((size_t)blockIdx.x * 256 + threadIdx.x) * 8;
    float4 a = *(const float4*)(wr + base);
    float4 b = *(const float4*)(wr + base + 4);
    u16x8 r;
    r[0] = f2bf(a.x); r[1] = f2bf(a.y); r[2] = f2bf(a.z); r[3] = f2bf(a.w);
    r[4] = f2bf(b.x); r[5] = f2bf(b.y); r[6] = f2bf(b.z); r[7] = f2bf(b.w);
    *(u16x8*)(wrh + base) = r;
}

// ---------------- kernel 1b: u [OUT,POOLS] -> uT [POOLS,OUT] ----------------
__global__ __launch_bounds__(256) void k_transpose_u(const float* __restrict__ u,
                                                     float* __restrict__ uT) {
    __shared__ float t[32][65];
    const int o0 = blockIdx.x * 64, p0 = blockIdx.y * 32;
    const int tid = threadIdx.x;
#pragma unroll
    for (int it = 0; it < 8; it++) {
        int o = (tid >> 5) + it * 8;
        t[tid & 31][o] = u[(size_t)(o0 + o) * N_POOL + p0 + (tid & 31)];
    }
    __syncthreads();
#pragma unroll
    for (int it = 0; it < 8; it++) {
        int p = (tid >> 6) + it * 4;
        uT[(size_t)(p0 + p) * N_OUT + o0 + (tid & 63)] = t[p][tid & 63];
    }
}

// ---------------- kernel 2: MFMA router, single-product bf16 + exact guarded fallback ------
// 512 thr / 8 waves, 32 tokens x 128 pools, BK=64, grid 256. Pure global_load_lds staging
// (counted vmcnt: waves 0-3 issue 3 loads/tile [1 A + 2 B], waves 4-7 issue 2 [B only]).
// Chunk-XOR LDS swizzle via pre-swizzled global source (round-2-proven algebra).
// bf16 logit error sigma ~3.5e-3; TAU=0.06 (~8 sigma for the v2-2eps candidate bound), so the
// fp32 fallback's candidate set provably contains the true top-2 => routing is fp32-exact.
#define RTK 64
#define TAU 0.06f

__global__ __launch_bounds__(512) void k_router(const float* __restrict__ x,
                                                const float* __restrict__ wr,
                                                const unsigned short* __restrict__ wrh,
                                                const unsigned short* __restrict__ xh,
                                                const float* __restrict__ svh,
                                                int* __restrict__ idxp,
                                                float* __restrict__ dotp) {
    __shared__ __attribute__((aligned(16))) unsigned short A2[2][32 * RTK];      //  4 KB x2
    __shared__ __attribute__((aligned(16))) unsigned short B2[2][N_POOL * RTK];  // 16 KB x2
    __shared__ float lg[32][N_POOL + 1];   // stride 129: conflict-free scan
    __shared__ float thr2[32];
    __shared__ int   flg[32];
    __shared__ int   sel[32][2];

    const int tid  = threadIdx.x;
    const int lane = tid & 63;
    const int w    = tid >> 6;          // wave 0..7
    const int wm   = w & 1;             // token half (16 tokens)
    const int wn   = w >> 1;            // pool group (32 pools)
    const int lrow = lane & 15, lquad = lane >> 4;
    const size_t m0 = (size_t)blockIdx.x * 32;
    const int srow8 = lane >> 3, schunk = lane & 7;

    f32x4 acc[2] = {};

    // waves 0-3: rows 8w..8w+7 of the 32x64 A tile (1 load); all waves: 2 B loads.
#define RSTAGE(bufi, kk)                                                                         \
    {                                                                                            \
        if (w < 4) {                                                                             \
            int rr = 8 * w + srow8; int cc = schunk ^ (rr & 7);                                  \
            __builtin_amdgcn_global_load_lds(                                                    \
                (const AS1 void*)(xh + (m0 + rr) * (size_t)K_DIM + (kk) + cc * 8),               \
                (AS3 void*)(&A2[bufi][8 * w * RTK] + lane * 8), 16, 0, 0);                       \
        }                                                                                        \
        _Pragma("unroll")                                                                        \
        for (int j = 0; j < 2; j++) {                                                            \
            int rr = 8 * w + 64 * j + srow8; int cc = schunk ^ (rr & 7);                         \
            __builtin_amdgcn_global_load_lds(                                                    \
                (const AS1 void*)(wrh + (size_t)rr * K_DIM + (kk) + cc * 8),                     \
                (AS3 void*)(&B2[bufi][(8 * w + 64 * j) * RTK] + lane * 8), 16, 0, 0);            \
        }                                                                                        \
    }

    RSTAGE(0, 0)
    RSTAGE(1, RTK)

    for (int t = 0; t < K_DIM / RTK; ++t) {
        if (t == 63)     asm volatile("s_waitcnt vmcnt(0)" ::: "memory");
        else if (w < 4)  asm volatile("s_waitcnt vmcnt(3)" ::: "memory");
        else             asm volatile("s_waitcnt vmcnt(2)" ::: "memory");
        __builtin_amdgcn_s_barrier();
        const int buf = t & 1;
#pragma unroll
        for (int ks = 0; ks < 2; ks++) {
            const int cs = ((ks * 4 + lquad) ^ (lrow & 7)) * 8;
            bf16x8 ah = *(const bf16x8*)&A2[buf][(wm * 16 + lrow) * RTK + cs];
#pragma unroll
            for (int nt = 0; nt < 2; nt++) {
                bf16x8 bh = *(const bf16x8*)&B2[buf][(wn * 32 + nt * 16 + lrow) * RTK + cs];
                acc[nt] = __builtin_amdgcn_mfma_f32_16x16x32_bf16(ah, bh, acc[nt], 0, 0, 0);
            }
        }
        __builtin_amdgcn_s_barrier();
        if (t < 62) RSTAGE(buf, (t + 2) * RTK)
    }
#undef RSTAGE

    // logits -> LDS (C/D layout: col=lane&15 -> pool, row=(lane>>4)*4+reg -> token)
#pragma unroll
    for (int nt = 0; nt < 2; nt++)
#pragma unroll
        for (int r = 0; r < 4; r++)
            lg[wm * 16 + lquad * 4 + r][wn * 32 + nt * 16 + lrow] = acc[nt][r];
    __syncthreads();

    if (tid < 32) {
        float v1 = -3.4e38f, v2 = -3.4e38f, v3 = -3.4e38f; int i1 = 0, i2 = 0;
        for (int p = 0; p < N_POOL; p++) {
            float v = lg[tid][p];
            if (v > v1)      { v3 = v2; v2 = v1; i2 = i1; v1 = v; i1 = p; }
            else if (v > v2) { v3 = v2; v2 = v;  i2 = p; }
            else if (v > v3) { v3 = v; }
        }
        sel[tid][0] = i1; sel[tid][1] = i2;
        thr2[tid] = v2 - TAU;
        flg[tid]  = (v2 - v3 < TAU) ? 1 : 0;
    }
    __syncthreads();

    // near-tie fallback: exact fp32 recompute of all candidate pools (>= v2-TAU)
    if (w == 0) {
        for (int s = 0; s < 32; s++) {
            if (!flg[s]) continue;
            const float th = thr2[s];
            unsigned long long c0 = __ballot(lg[s][lane] >= th);
            unsigned long long c1 = __ballot(lg[s][64 + lane] >= th);
            float v1 = -3.4e38f, v2 = -3.4e38f; int i1 = 0, i2 = 0;
            const float* xr = x + (m0 + s) * K_DIM;
            for (int half = 0; half < 2; half++) {
                unsigned long long m = half ? c1 : c0;
                while (m) {
                    const int p = (half ? 64 : 0) + __ffsll(m) - 1;
                    m &= m - 1;
                    const float* wp = wr + (size_t)p * K_DIM;
                    float d = 0.f;
#pragma unroll 8
                    for (int it = 0; it < 64; it++)
                        d += xr[it * 64 + lane] * wp[it * 64 + lane];
#pragma unroll
                    for (int off = 32; off > 0; off >>= 1) d += __shfl_down(d, off);
                    d = __shfl(d, 0);
                    if (d > v1)      { v2 = v1; i2 = i1; v1 = d; i1 = p; }
                    else if (d > v2) { v2 = d; i2 = p; }
                }
            }
            if (lane == 0) { sel[s][0] = i1; sel[s][1] = i2; }
        }
    }
    __syncthreads();

    if (tid < 32) {
        idxp[(m0 + tid) * 2 + 0] = sel[tid][0];
        idxp[(m0 + tid) * 2 + 1] = sel[tid][1];
    }

    // svh dots: one wave per token; x read as bf16 (xh plane), same values as prior rounds
    for (int s = w; s < 32; s += 8) {
        const size_t n = m0 + s;
        const int e0 = sel[s][0], e1 = sel[s][1];
        float d0 = 0.f, d1 = 0.f;
#pragma unroll
        for (int it = 0; it < 8; it++) {
            const int e = (it * 64 + lane) * 8;
            u16x8 xv = *(const u16x8*)(xh + n * K_DIM + e);
            float4 s0 = *(const float4*)(svh + (size_t)e0 * K_DIM + e);
            float4 s1 = *(const float4*)(svh + (size_t)e0 * K_DIM + e + 4);
            float4 s2 = *(const float4*)(svh + (size_t)e1 * K_DIM + e);
            float4 s3 = *(const float4*)(svh + (size_t)e1 * K_DIM + e + 4);
            float x0 = bf2f(xv[0]), x1 = bf2f(xv[1]), x2 = bf2f(xv[2]), x3 = bf2f(xv[3]);
            float x4 = bf2f(xv[4]), x5 = bf2f(xv[5]), x6 = bf2f(xv[6]), x7 = bf2f(xv[7]);
            d0 += x0*s0.x + x1*s0.y + x2*s0.z + x3*s0.w + x4*s1.x + x5*s1.y + x6*s1.z + x7*s1.w;
            d1 += x0*s2.x + x1*s2.y + x2*s2.z + x3*s2.w + x4*s3.x + x5*s3.y + x6*s3.z + x7*s3.w;
        }
#pragma unroll
        for (int off = 32; off > 0; off >>= 1) {
            d0 += __shfl_down(d0, off);
            d1 += __shfl_down(d1, off);
        }
        if (lane == 0) { dotp[n * 2 + 0] = d0; dotp[n * 2 + 1] = d1; }
    }
}

// ---------------- kernel 3: 256x256 double-buffered bf16 MFMA GEMM (round-2 proven body) ----
__global__ __launch_bounds__(512) void k_gemm(const unsigned short* __restrict__ xh,
                                              const unsigned short* __restrict__ w0b,
                                              const float* __restrict__ b0,
                                              const float* __restrict__ uT,
                                              const int* __restrict__ idxp,
                                              const float* __restrict__ dotp,
                                              float* __restrict__ out) {
    __shared__ __attribute__((aligned(16))) unsigned short Als[2][256 * 64];  // 64 KB
    __shared__ __attribute__((aligned(16))) unsigned short Bls[2][256 * 64];  // 64 KB

    const int tid  = threadIdx.x;
    const int lane = tid & 63;
    const int w    = tid >> 6;
    const int wm   = w >> 2, wn = w & 3;          // 2 x 4 wave grid
    const int lrow = lane & 15, lquad = lane >> 4;

    // bijective XCD swizzle (nwg=512, 512%8==0)
    const int lgid = (blockIdx.x & 7) * 64 + (blockIdx.x >> 3);
    const size_t n0 = (size_t)(lgid & 15) * 256;
    const size_t m0 = (size_t)(lgid >> 4) * 256;

    const int srow   = tid >> 3;                  // 0..63
    const int xchunk = (tid & 7) ^ (srow & 7);
    const unsigned short* ag = xh  + (m0 + srow) * K_DIM + xchunk * 8;
    const unsigned short* bg = w0b + (n0 + srow) * K_DIM + xchunk * 8;

    f32x4 acc[8][4] = {};

#define STAGE(buf, k0)                                                                        \
    {                                                                                         \
        unsigned short* al = &Als[buf][tid * 8];                                              \
        unsigned short* bl = &Bls[buf][tid * 8];                                              \
        _Pragma("unroll")                                                                     \
        for (int l = 0; l < 4; l++) {                                                         \
            __builtin_amdgcn_global_load_lds(                                                 \
                (const AS1 void*)(ag + (size_t)l * 64 * K_DIM + (k0)),                        \
                (AS3 void*)(al + l * 4096), 16, 0, 0);                                        \
            __builtin_amdgcn_global_load_lds(                                                 \
                (const AS1 void*)(bg + (size_t)l * 64 * K_DIM + (k0)),                        \
                (AS3 void*)(bl + l * 4096), 16, 0, 0);                                        \
        }                                                                                     \
    }

#define COMPUTE(buf)                                                                          \
    {                                                                                         \
        _Pragma("unroll")                                                                     \
        for (int ks = 0; ks < 2; ks++) {                                                      \
            const int cs = ((ks * 4 + lquad) ^ (lrow & 7)) * 8;                               \
            bf16x8 bfv[4];                                                                    \
            _Pragma("unroll")                                                                 \
            for (int nt = 0; nt < 4; nt++)                                                    \
                bfv[nt] = *(const bf16x8*)&Bls[buf][(wn * 64 + nt * 16 + lrow) * 64 + cs];    \
            _Pragma("unroll")                                                                 \
            for (int mt = 0; mt < 8; mt++) {                                                  \
                bf16x8 av = *(const bf16x8*)&Als[buf][(wm * 128 + mt * 16 + lrow) * 64 + cs]; \
                _Pragma("unroll")                                                             \
                for (int nt = 0; nt < 4; nt++)                                                \
                    acc[mt][nt] = __builtin_amdgcn_mfma_f32_16x16x32_bf16(av, bfv[nt], acc[mt][nt], 0, 0, 0); \
            }                                                                                 \
        }                                                                                     \
    }

    STAGE(0, 0)
    STAGE(1, 64)

    for (int t = 0; t < 63; ++t) {
        asm volatile("s_waitcnt vmcnt(8)" ::: "memory");   // tile t landed; t+1 stays in flight
        __builtin_amdgcn_s_barrier();
        const int buf = t & 1;
        COMPUTE(buf)
        __builtin_amdgcn_s_barrier();                      // all reads of buf done
        if (t < 62) STAGE(buf, (t + 2) * 64)               // prefetch tile t+2 into freed buf
    }
    asm volatile("s_waitcnt vmcnt(0)" ::: "memory");
    __builtin_amdgcn_s_barrier();
    COMPUTE(1)

#undef STAGE
#undef COMPUTE

    // epilogue: C/D layout col=lane&15, row=(lane>>4)*4+reg (m89-verified)
    float b0v[4];
#pragma unroll
    for (int nt = 0; nt < 4; nt++) b0v[nt] = b0[n0 + wn * 64 + nt * 16 + lrow];
#pragma unroll
    for (int mt = 0; mt < 8; mt++) {
        const size_t rb = m0 + wm * 128 + mt * 16 + lquad * 4;
#pragma unroll
        for (int r = 0; r < 4; r++) {
            const size_t gm = rb + r;
            const int e0 = idxp[gm * 2 + 0], e1 = idxp[gm * 2 + 1];
            const float dd0 = dotp[gm * 2 + 0], dd1 = dotp[gm * 2 + 1];
#pragma unroll
            for (int nt = 0; nt < 4; nt++) {
                const size_t gn = n0 + wn * 64 + nt * 16 + lrow;
                float vv = acc[mt][nt][r] + b0v[nt]
                         + dd0 * uT[(size_t)e0 * N_OUT + gn] + dd1 * uT[(size_t)e1 * N_OUT + gn];
                out[gm * N_OUT + gn] = vv;
            }
        }
    }
}

extern "C" void kernel_launch(void* const* d_in, const int* in_sizes, int n_in,
                              void* d_out, int out_size, void* d_ws, size_t ws_size,
                              hipStream_t stream) {
    const float* x   = (const float*)d_in[0];  // [8192, 4096]
    const float* w0  = (const float*)d_in[1];  // [4096, 4096]
    const float* b0  = (const float*)d_in[2];  // [4096]
    const float* wr  = (const float*)d_in[3];  // [128, 4096]
    const float* u   = (const float*)d_in[4];  // [4096, 128]
    const float* svh = (const float*)d_in[5];  // [128, 4096]
    float* out = (float*)d_out;

    // workspace layout (~99.1 MiB -- back under the harness-proven round-1/2 budget)
    char* ws = (char*)d_ws;
    unsigned short* xh  = (unsigned short*)ws;                       // 8192*4096*2 = 67108864 B
    unsigned short* w0b = (unsigned short*)(ws + 67108864);          // 4096*4096*2 = 33554432 B
    int*   idxp = (int*)(ws + 100663296);                            // 65536 B
    float* dotp = (float*)(ws + 100663296 + 65536);                  // 65536 B
    float* uTp  = (float*)(ws + 100663296 + 131072);                 // 2097152 B
    unsigned short* wrh = (unsigned short*)(ws + 102891520);         // 1048576 B  (ends 103940096)

    k_convert_w0<<<dim3(16777216 / (256 * 8)), dim3(256), 0, stream>>>(w0, w0b);
    k_convert_x<<<dim3(33554432 / (256 * 8)), dim3(256), 0, stream>>>(x, xh);
    k_convert_wr<<<dim3(524288 / (256 * 8)), dim3(256), 0, stream>>>(wr, wrh);
    k_transpose_u<<<dim3(N_OUT / 64, N_POOL / 32), dim3(256), 0, stream>>>(u, uTp);
    k_router<<<dim3(N_TOK / 32), dim3(512), 0, stream>>>(x, wr, wrh, xh, svh, idxp, dotp);
    k_gemm<<<dim3(512), dim3(512), 0, stream>>>(xh, w0b, b0, uTp, idxp, dotp, out);
}